// Round 2
// baseline (211.252 us; speedup 1.0000x reference)
//
#include <hip/hip_runtime.h>

// CountHistogram: B=64, C=4, Q=32, D=4096, NBINS=29
// out[b,c,q,bin] = sum_d mask[b,q,d] * (bin == trunc((simmat[b,c,q,d]+1.00001)/2*28))
//
// R7: single-variable A/B on the last untested subsystem — the global-load
// path. Evidence so far: R0 (fully serialized same-address ds_add), R2
// (conflict-free replicated ds_add), R5 (non-atomic privatized RMW), R6
// (u16-packed hist, 8 blocks/CU vs 5) are ALL within +/-1.5us, which equals
// the poison-fill jitter (77.6-79us x2 in the timed region). Serialized vs
// conflict-free LDS being indistinguishable means nothing downstream of the
// loads is on the critical path -> kernel is paced by the HBM read stream
// (167.8 MB mandatory = 26.6us floor @ 6.3 TB/s).
// The one untested variable from R3: __builtin_nontemporal_load on simmat.
// This round removes it (plain cached load); everything else byte-identical
// to R6. Prediction: neutral (+/-2us) -> load path exhausted, kernel at its
// HBM floor, declare roofline; if -5..15us, nt was capping streaming reads.
//
// Kept from R6: packed u16 hist (2 bins/u32, per-lane-column counts <= 64,
// no overflow), LDS 15,360 B/block -> 8 blocks/CU, __launch_bounds__(256,8),
// unroll 4, non-atomic per-lane-column privatized RMW (lane owns column
// `lane`, bank = lane&31 -> 2 lanes/bank distinct dwords = free tier),
// 2-lanes-per-bin rotated epilogue + __shfl_down(32) combine.

constexpr int Bdim  = 64;
constexpr int Cdim  = 4;
constexpr int Qdim  = 32;
constexpr int Ddim  = 4096;
constexpr int NBINS = 29;
constexpr int NROWS = (NBINS + 1) / 2;    // 15 word-rows, 2 bins packed per u32
constexpr int NCOPY = 64;                 // one private column per lane
constexpr int WHIST = NROWS * NCOPY;      // 960 words per wave

typedef float vf4 __attribute__((ext_vector_type(4)));
typedef int   vi4 __attribute__((ext_vector_type(4)));

__global__ __launch_bounds__(256, 8) void CountHistogram_33809982554604_kernel(
    const float* __restrict__ simmat,   // [B,C,Q,D] f32
    const int*   __restrict__ mask,     // [B,Q,D]   int32 (0/1)
    float*       __restrict__ out)      // [B,C,Q,NBINS] f32
{
    __shared__ unsigned int hist[4][WHIST];   // 15,360 B total -> 8 blocks/CU

    const int bq   = blockIdx.x;          // 0 .. B*Q-1
    const int b    = bq >> 5;             // Q = 32
    const int q    = bq & 31;
    const int wave = threadIdx.x >> 6;    // = c
    const int lane = threadIdx.x & 63;

    unsigned int* __restrict__ h = hist[wave];

    // zero this wave's private columns (wave-private: lockstep, no barrier)
    #pragma unroll
    for (int i = lane; i < WHIST; i += 64) h[i] = 0u;   // 15 iters

    const float* __restrict__ srow =
        simmat + (((size_t)b * Cdim + wave) * Qdim + q) * Ddim;
    const int* __restrict__ mrow =
        mask + ((size_t)b * Qdim + q) * Ddim;

    #pragma unroll 4
    for (int j = 0; j < Ddim / 256; ++j) {      // 16 iterations
        const int idx = (j * 64 + lane) * 4;    // element index of this lane's float4
        // R7 A/B: simmat via plain cached load (was __builtin_nontemporal_load)
        const vf4 x = *reinterpret_cast<const vf4*>(srow + idx);
        // mask: reused by all 4 waves of this block -> normal cached load
        const vi4 m = *reinterpret_cast<const vi4*>(mrow + idx);

        // (x+1.00001f)*14.0f is bit-identical to ((x+1.00001)/2)*28:
        // /2 is exact, single rounding on the *14 either way.
        int b0 = (int)((x.x + 1.00001f) * 14.0f);
        int b1 = (int)((x.y + 1.00001f) * 14.0f);
        int b2 = (int)((x.z + 1.00001f) * 14.0f);
        int b3 = (int)((x.w + 1.00001f) * 14.0f);
        b0 = min(b0, NBINS - 1);
        b1 = min(b1, NBINS - 1);
        b2 = min(b2, NBINS - 1);
        b3 = min(b3, NBINS - 1);

        // packed u16 RMW: word = bin>>1, halfword = bin&1; lane owns column
        // `lane` -> no aliasing within the wave, program-ordered per lane.
        h[(b0 >> 1) * NCOPY + lane] += (unsigned int)m.x << ((b0 & 1) << 4);
        h[(b1 >> 1) * NCOPY + lane] += (unsigned int)m.y << ((b1 & 1) << 4);
        h[(b2 >> 1) * NCOPY + lane] += (unsigned int)m.z << ((b2 & 1) << 4);
        h[(b3 >> 1) * NCOPY + lane] += (unsigned int)m.w << ((b3 & 1) << 4);
    }

    // compiler fence: LDS writes above complete (in wave-order) before the
    // cross-lane reads below; lanes of one wave run in lockstep, no s_barrier.
    __builtin_amdgcn_wave_barrier();

    // Epilogue: 2 lanes per bin. Lane l (l&31 = bin) sums column half
    // cb = (l>=32)*32; rotation (i+lane)&31 keeps lanes on distinct banks
    // (word%32 = col%32 since row stride 64 == 0 mod 32) -> 2-way free tier.
    const int bin = lane & 31;
    unsigned int sum = 0u;
    if (bin < NBINS) {
        const int w  = bin >> 1;
        const int sh = (bin & 1) << 4;
        const int cb = (lane >> 5) << 5;    // 0 or 32
        const unsigned int* __restrict__ hr = h + w * NCOPY + cb;
        #pragma unroll
        for (int i = 0; i < 32; ++i) {
            const int c = (i + lane) & 31;
            sum += (hr[c] >> sh) & 0xffffu;
        }
    }
    // combine column halves: lane l (<29) += lane l+32's partial
    const unsigned int other = (unsigned int)__shfl_down((int)sum, 32, 64);
    if (lane < NBINS) {
        out[(((size_t)b * Cdim + wave) * Qdim + q) * NBINS + lane] =
            (float)(sum + other);
    }
}

extern "C" void kernel_launch(void* const* d_in, const int* in_sizes, int n_in,
                              void* d_out, int out_size, void* d_ws, size_t ws_size,
                              hipStream_t stream) {
    const float* simmat = (const float*)d_in[0];
    const int*   mask   = (const int*)d_in[1];
    float*       out    = (float*)d_out;

    dim3 grid(Bdim * Qdim);   // 2048 blocks: one per (b,q)
    dim3 block(256);          // 4 waves: one per c
    CountHistogram_33809982554604_kernel<<<grid, block, 0, stream>>>(simmat, mask, out);
}

// Round 3
// 201.138 us; speedup vs baseline: 1.0503x; 1.0503x over previous
//
#include <hip/hip_runtime.h>

// CountHistogram: B=64, C=4, Q=32, D=4096, NBINS=29
// out[b,c,q,bin] = sum_d mask[b,q,d] * (bin == trunc((simmat[b,c,q,d]+1.00001)/2*28))
//
// R8: mask-in-LDS round. R7's A/B (drop nontemporal on simmat) regressed
// +11us — the one µs-scale mechanism found: the mask row (16 KiB, read by
// all 4 waves of a block; 32 MiB compulsory) gets re-fetched from HBM when
// the simmat stream thrashes L1/L2 (per-XCD mask working set = 32 CU x 8
// blk x 16 KiB = 4 MiB = exactly L2 capacity). nt on simmat protects it
// (evict-first), worth 11us. But nt is only a hint — residual mask
// re-fetch may remain in the nt config (kernel ~44us vs 26.6us compulsory
// floor). This round makes re-fetch structurally impossible: stage the
// mask row into LDS once per block (coalesced, 1 barrier), hot loop reads
// it via ds_read_b128. Guarantees mask HBM = 32 MiB once; also removes one
// VMEM stream from the loop. LDS 15,360 -> 31,744 B/block -> 5 blocks/CU;
// R5 proved 5 blocks/CU is neutral (no residency confound).
// nt on simmat RESTORED (mandated by R7 A/B).
//
// Kept from R6: packed u16 hist (2 bins/u32, per-lane-column counts <= 64,
// no overflow/carry), non-atomic per-lane-column privatized RMW (lane owns
// column `lane`, bank = lane&31 -> 2 lanes/bank distinct dwords = free
// tier, m136), unroll 4, 2-lanes-per-bin rotated epilogue + __shfl_down(32).

constexpr int Bdim  = 64;
constexpr int Cdim  = 4;
constexpr int Qdim  = 32;
constexpr int Ddim  = 4096;
constexpr int NBINS = 29;
constexpr int NROWS = (NBINS + 1) / 2;    // 15 word-rows, 2 bins packed per u32
constexpr int NCOPY = 64;                 // one private column per lane
constexpr int WHIST = NROWS * NCOPY;      // 960 words per wave

typedef float vf4 __attribute__((ext_vector_type(4)));
typedef int   vi4 __attribute__((ext_vector_type(4)));

__global__ __launch_bounds__(256, 5) void CountHistogram_33809982554604_kernel(
    const float* __restrict__ simmat,   // [B,C,Q,D] f32
    const int*   __restrict__ mask,     // [B,Q,D]   int32 (0/1)
    float*       __restrict__ out)      // [B,C,Q,NBINS] f32
{
    __shared__ unsigned int hist[4][WHIST];   // 15,360 B
    __shared__ int smask[Ddim];               // 16,384 B  (31,744 total -> 5 blk/CU)

    const int bq   = blockIdx.x;          // 0 .. B*Q-1
    const int b    = bq >> 5;             // Q = 32
    const int q    = bq & 31;
    const int wave = threadIdx.x >> 6;    // = c
    const int lane = threadIdx.x & 63;

    unsigned int* __restrict__ h = hist[wave];

    // zero this wave's private columns (wave-private: lockstep, no barrier)
    #pragma unroll
    for (int i = lane; i < WHIST; i += 64) h[i] = 0u;   // 15 iters

    const float* __restrict__ srow =
        simmat + (((size_t)b * Cdim + wave) * Qdim + q) * Ddim;
    const int* __restrict__ mrow =
        mask + ((size_t)b * Qdim + q) * Ddim;

    // Stage the block's mask row (16 KiB) into LDS once: 4 rounds x 256
    // threads x 16 B, fully coalesced. After this, mask HBM traffic is
    // exactly 32 MiB kernel-wide regardless of cache behavior.
    #pragma unroll
    for (int r = 0; r < 4; ++r) {
        const int e = (r * 256 + threadIdx.x) * 4;   // element index
        *reinterpret_cast<vi4*>(smask + e) =
            *reinterpret_cast<const vi4*>(mrow + e);
    }
    __syncthreads();

    #pragma unroll 4
    for (int j = 0; j < Ddim / 256; ++j) {      // 16 iterations
        const int idx = (j * 64 + lane) * 4;    // element index of this lane's float4
        // simmat: read-once stream -> nontemporal (R7 A/B: worth ~11us)
        const vf4 x = __builtin_nontemporal_load(
            reinterpret_cast<const vf4*>(srow + idx));
        // mask: from LDS (ds_read_b128, stride-1 16B/lane = conflict-free)
        const vi4 m = *reinterpret_cast<const vi4*>(smask + idx);

        // (x+1.00001f)*14.0f is bit-identical to ((x+1.00001)/2)*28:
        // /2 is exact, single rounding on the *14 either way.
        int b0 = (int)((x.x + 1.00001f) * 14.0f);
        int b1 = (int)((x.y + 1.00001f) * 14.0f);
        int b2 = (int)((x.z + 1.00001f) * 14.0f);
        int b3 = (int)((x.w + 1.00001f) * 14.0f);
        // clamp kept for LDS-bounds safety on any out-of-range input
        b0 = min(b0, NBINS - 1);
        b1 = min(b1, NBINS - 1);
        b2 = min(b2, NBINS - 1);
        b3 = min(b3, NBINS - 1);

        // packed u16 RMW: word = bin>>1, halfword = bin&1; lane owns column
        // `lane` -> no aliasing within the wave, program-ordered per lane.
        h[(b0 >> 1) * NCOPY + lane] += (unsigned int)m.x << ((b0 & 1) << 4);
        h[(b1 >> 1) * NCOPY + lane] += (unsigned int)m.y << ((b1 & 1) << 4);
        h[(b2 >> 1) * NCOPY + lane] += (unsigned int)m.z << ((b2 & 1) << 4);
        h[(b3 >> 1) * NCOPY + lane] += (unsigned int)m.w << ((b3 & 1) << 4);
    }

    // compiler fence: LDS writes above complete (in wave-order) before the
    // cross-lane reads below; lanes of one wave run in lockstep, no s_barrier.
    __builtin_amdgcn_wave_barrier();

    // Epilogue: 2 lanes per bin. Lane l (l&31 = bin) sums column half
    // cb = (l>=32)*32; rotation (i+lane)&31 keeps lanes on distinct banks
    // (word%32 = col%32 since row stride 64 == 0 mod 32) -> 2-way free tier.
    const int bin = lane & 31;
    unsigned int sum = 0u;
    if (bin < NBINS) {
        const int w  = bin >> 1;
        const int sh = (bin & 1) << 4;
        const int cb = (lane >> 5) << 5;    // 0 or 32
        const unsigned int* __restrict__ hr = h + w * NCOPY + cb;
        #pragma unroll
        for (int i = 0; i < 32; ++i) {
            const int c = (i + lane) & 31;
            sum += (hr[c] >> sh) & 0xffffu;
        }
    }
    // combine column halves: lane l (<29) += lane l+32's partial
    const unsigned int other = (unsigned int)__shfl_down((int)sum, 32, 64);
    if (lane < NBINS) {
        out[(((size_t)b * Cdim + wave) * Qdim + q) * NBINS + lane] =
            (float)(sum + other);
    }
}

extern "C" void kernel_launch(void* const* d_in, const int* in_sizes, int n_in,
                              void* d_out, int out_size, void* d_ws, size_t ws_size,
                              hipStream_t stream) {
    const float* simmat = (const float*)d_in[0];
    const int*   mask   = (const int*)d_in[1];
    float*       out    = (float*)d_out;

    dim3 grid(Bdim * Qdim);   // 2048 blocks: one per (b,q)
    dim3 block(256);          // 4 waves: one per c
    CountHistogram_33809982554604_kernel<<<grid, block, 0, stream>>>(simmat, mask, out);
}